// Round 1
// baseline (4481.585 us; speedup 1.0000x reference)
//
#include <hip/hip_runtime.h>

// GNN: 3x (GraphConv -> BatchNorm -> ReLU) -> global_mean_pool -> Linear
// All fp32. Integer inputs (edge_index, batch) arrive as int32 per harness convention.
//
// Workspace layout (needs ~77.4 MB of d_ws):
//   agg   : N*H fp32  (25.6 MB)
//   hA    : N*H fp32  (25.6 MB)
//   hB    : N*H fp32  (25.6 MB)
//   stats : 256 fp32  (colsum[128], colsumsq[128])
//   pooled: G*H fp32  (512 KB)
//   counts: G  int32  (4 KB)

constexpr int   NN   = 50000;
constexpr int   NE   = 800000;
constexpr int   DH   = 128;
constexpr int   NC   = 10;
constexpr int   NG   = 1024;
constexpr float EPSV = 1e-5f;

// ---------------------------------------------------------------- scatter ---
// 32 threads per edge; each thread moves 4 floats (float4 gather + 4 atomics).
__global__ __launch_bounds__(256) void scatter_add_kernel(
    const float* __restrict__ x, const int* __restrict__ src,
    const int* __restrict__ dst, float* __restrict__ agg)
{
    int tid = blockIdx.x * 256 + threadIdx.x;
    int e = tid >> 5;
    if (e >= NE) return;
    int c4 = (tid & 31) << 2;
    int s = src[e], d = dst[e];
    float4 v = *reinterpret_cast<const float4*>(x + (size_t)s * DH + c4);
    float* o = agg + (size_t)d * DH + c4;
    atomicAdd(o + 0, v.x);
    atomicAdd(o + 1, v.y);
    atomicAdd(o + 2, v.z);
    atomicAdd(o + 3, v.w);
}

// ------------------------------------------------------------------- gemm ---
// OUT(N x 128) = X @ Wr + A @ Wl + bias   (K = 128 each, concat K = 256)
// Block: 256 threads, 64 rows x 128 cols tile; thread: 4 rows x 8 cols.
__global__ __launch_bounds__(256) void gemm_fused_kernel(
    const float* __restrict__ X, const float* __restrict__ A,
    const float* __restrict__ Wr, const float* __restrict__ Wl,
    const float* __restrict__ bias, float* __restrict__ OUT)
{
    __shared__ float sA[64][33];   // +1 pad: conflict-free column reads
    __shared__ float sW[32][128];

    const int tid = threadIdx.x;
    const int tx8 = (tid & 15) * 8;   // col offset 0..120
    const int ty4 = (tid >> 4) * 4;   // row offset 0..60
    const int row0 = blockIdx.x * 64;

    float acc[4][8];
#pragma unroll
    for (int r = 0; r < 4; ++r)
#pragma unroll
        for (int j = 0; j < 8; ++j) acc[r][j] = 0.f;

    const int rA = tid >> 2;        // 0..63
    const int cA = (tid & 3) * 4;   // 0,4,8,12

    for (int k0 = 0; k0 < 256; k0 += 32) {
        const float* inp = (k0 < 128) ? X : A;
        const float* W   = (k0 < 128) ? Wr : Wl;
        const int kb = k0 & 127;

        // stage A tile: 64 rows x 32 k
        {
            int grow = row0 + rA;
            float4 v0 = make_float4(0.f, 0.f, 0.f, 0.f), v1 = v0;
            if (grow < NN) {
                const float* p = inp + (size_t)grow * DH + kb + cA;
                v0 = *reinterpret_cast<const float4*>(p);
                v1 = *reinterpret_cast<const float4*>(p + 16);
            }
            sA[rA][cA + 0]  = v0.x; sA[rA][cA + 1]  = v0.y;
            sA[rA][cA + 2]  = v0.z; sA[rA][cA + 3]  = v0.w;
            sA[rA][cA + 16] = v1.x; sA[rA][cA + 17] = v1.y;
            sA[rA][cA + 18] = v1.z; sA[rA][cA + 19] = v1.w;
        }
        // stage W tile: 32 k x 128 cols
#pragma unroll
        for (int i = 0; i < 4; ++i) {
            int idx = tid + i * 256;            // float4 index 0..1023
            int kk = idx >> 5;                  // 32 float4 per row
            int cc = (idx & 31) * 4;
            *reinterpret_cast<float4*>(&sW[kk][cc]) =
                *reinterpret_cast<const float4*>(W + (size_t)(kb + kk) * DH + cc);
        }
        __syncthreads();

#pragma unroll 8
        for (int kk = 0; kk < 32; ++kk) {
            float a0 = sA[ty4 + 0][kk];
            float a1 = sA[ty4 + 1][kk];
            float a2 = sA[ty4 + 2][kk];
            float a3 = sA[ty4 + 3][kk];
            float4 w0 = *reinterpret_cast<const float4*>(&sW[kk][tx8]);
            float4 w1 = *reinterpret_cast<const float4*>(&sW[kk][tx8 + 4]);
            float wv[8] = {w0.x, w0.y, w0.z, w0.w, w1.x, w1.y, w1.z, w1.w};
#pragma unroll
            for (int j = 0; j < 8; ++j) {
                acc[0][j] = fmaf(a0, wv[j], acc[0][j]);
                acc[1][j] = fmaf(a1, wv[j], acc[1][j]);
                acc[2][j] = fmaf(a2, wv[j], acc[2][j]);
                acc[3][j] = fmaf(a3, wv[j], acc[3][j]);
            }
        }
        __syncthreads();
    }

    float bv[8];
#pragma unroll
    for (int j = 0; j < 8; ++j) bv[j] = bias[tx8 + j];

#pragma unroll
    for (int r = 0; r < 4; ++r) {
        int grow = row0 + ty4 + r;
        if (grow < NN) {
            float4 o0, o1;
            o0.x = acc[r][0] + bv[0]; o0.y = acc[r][1] + bv[1];
            o0.z = acc[r][2] + bv[2]; o0.w = acc[r][3] + bv[3];
            o1.x = acc[r][4] + bv[4]; o1.y = acc[r][5] + bv[5];
            o1.z = acc[r][6] + bv[6]; o1.w = acc[r][7] + bv[7];
            float* op = OUT + (size_t)grow * DH + tx8;
            *reinterpret_cast<float4*>(op)     = o0;
            *reinterpret_cast<float4*>(op + 4) = o1;
        }
    }
}

// ------------------------------------------------------------------ stats ---
__global__ __launch_bounds__(128) void col_stats_kernel(
    const float* __restrict__ H, float* __restrict__ stats)
{
    int col = threadIdx.x;   // 128 threads: one per column, coalesced row reads
    float s = 0.f, ss = 0.f;
    for (int r = blockIdx.x; r < NN; r += gridDim.x) {
        float v = H[(size_t)r * DH + col];
        s += v;
        ss += v * v;
    }
    atomicAdd(&stats[col], s);
    atomicAdd(&stats[DH + col], ss);
}

template <bool RELU>
__global__ __launch_bounds__(256) void bn_act_kernel(
    float* __restrict__ Hio, const float* __restrict__ stats,
    const float* __restrict__ gamma, const float* __restrict__ beta)
{
    __shared__ float sscale[DH], sshift[DH];
    if (threadIdx.x < DH) {
        int j = threadIdx.x;
        float mean = stats[j] * (1.f / NN);
        float var  = stats[DH + j] * (1.f / NN) - mean * mean;
        float sc = rsqrtf(var + EPSV) * gamma[j];
        sscale[j] = sc;
        sshift[j] = beta[j] - mean * sc;
    }
    __syncthreads();

    const int total4 = NN * (DH / 4);   // 1.6M float4
    for (int i = blockIdx.x * 256 + threadIdx.x; i < total4; i += gridDim.x * 256) {
        float4 v = reinterpret_cast<float4*>(Hio)[i];
        int j0 = (i & 31) * 4;
        v.x = v.x * sscale[j0 + 0] + sshift[j0 + 0];
        v.y = v.y * sscale[j0 + 1] + sshift[j0 + 1];
        v.z = v.z * sscale[j0 + 2] + sshift[j0 + 2];
        v.w = v.w * sscale[j0 + 3] + sshift[j0 + 3];
        if (RELU) {
            v.x = fmaxf(v.x, 0.f); v.y = fmaxf(v.y, 0.f);
            v.z = fmaxf(v.z, 0.f); v.w = fmaxf(v.w, 0.f);
        }
        reinterpret_cast<float4*>(Hio)[i] = v;
    }
}

// ------------------------------------------------------------------- pool ---
__global__ __launch_bounds__(256) void pool_kernel(
    const float* __restrict__ H, const int* __restrict__ batch,
    float* __restrict__ pooled, int* __restrict__ counts)
{
    int tid = blockIdx.x * 256 + threadIdx.x;
    int node = tid >> 5;
    if (node >= NN) return;
    int c4 = (tid & 31) << 2;
    int g = batch[node];
    float4 v = *reinterpret_cast<const float4*>(H + (size_t)node * DH + c4);
    float* p = pooled + (size_t)g * DH + c4;
    atomicAdd(p + 0, v.x);
    atomicAdd(p + 1, v.y);
    atomicAdd(p + 2, v.z);
    atomicAdd(p + 3, v.w);
    if (c4 == 0) atomicAdd(&counts[g], 1);
}

__global__ __launch_bounds__(64) void classify_kernel(
    const float* __restrict__ pooled, const int* __restrict__ counts,
    const float* __restrict__ wcls, const float* __restrict__ bcls,
    float* __restrict__ out)
{
    int g = blockIdx.x;
    int lane = threadIdx.x;   // 64
    float inv = 1.f / fmaxf((float)counts[g], 1.f);
    float p0 = pooled[(size_t)g * DH + lane] * inv;
    float p1 = pooled[(size_t)g * DH + 64 + lane] * inv;
#pragma unroll
    for (int c = 0; c < NC; ++c) {
        float v = p0 * wcls[lane * NC + c] + p1 * wcls[(64 + lane) * NC + c];
#pragma unroll
        for (int off = 32; off > 0; off >>= 1) v += __shfl_down(v, off, 64);
        if (lane == 0) out[(size_t)g * NC + c] = v + bcls[c];
    }
}

// ----------------------------------------------------------------- launch ---
extern "C" void kernel_launch(void* const* d_in, const int* in_sizes, int n_in,
                              void* d_out, int out_size, void* d_ws, size_t ws_size,
                              hipStream_t stream)
{
    const float* x    = (const float*)d_in[0];
    const int*   ei   = (const int*)d_in[1];
    const int*   batch= (const int*)d_in[2];
    const float* wr1  = (const float*)d_in[3];
    const float* wl1  = (const float*)d_in[4];
    const float* b1   = (const float*)d_in[5];
    const float* wr2  = (const float*)d_in[6];
    const float* wl2  = (const float*)d_in[7];
    const float* b2   = (const float*)d_in[8];
    const float* wr3  = (const float*)d_in[9];
    const float* wl3  = (const float*)d_in[10];
    const float* b3   = (const float*)d_in[11];
    const float* g1   = (const float*)d_in[12];
    const float* be1  = (const float*)d_in[13];
    const float* g2   = (const float*)d_in[14];
    const float* be2  = (const float*)d_in[15];
    const float* g3   = (const float*)d_in[16];
    const float* be3  = (const float*)d_in[17];
    const float* wcls = (const float*)d_in[18];
    const float* bcls = (const float*)d_in[19];
    float* out = (float*)d_out;

    const int* srcp = ei;
    const int* dstp = ei + NE;

    char* ws = (char*)d_ws;
    const size_t featB = (size_t)NN * DH * sizeof(float);   // 25,600,000 B
    float* agg    = (float*)(ws);
    float* hA     = (float*)(ws + featB);
    float* hB     = (float*)(ws + 2 * featB);
    float* stats  = (float*)(ws + 3 * featB);               // 1024 B
    float* pooled = (float*)(ws + 3 * featB + 1024);        // 524,288 B
    int*   counts = (int*)(ws + 3 * featB + 1024 + (size_t)NG * DH * sizeof(float));

    const int scatterBlocks = (NE * 32) / 256;   // 100000
    const int gemmBlocks    = (NN + 63) / 64;    // 782
    const int bnBlocks      = 2048;
    const int poolBlocks    = (NN * 32 + 255) / 256;

    // ---- layer 1
    hipMemsetAsync(agg, 0, featB, stream);
    scatter_add_kernel<<<scatterBlocks, 256, 0, stream>>>(x, srcp, dstp, agg);
    gemm_fused_kernel<<<gemmBlocks, 256, 0, stream>>>(x, agg, wr1, wl1, b1, hA);
    hipMemsetAsync(stats, 0, 1024, stream);
    col_stats_kernel<<<512, 128, 0, stream>>>(hA, stats);
    bn_act_kernel<true><<<bnBlocks, 256, 0, stream>>>(hA, stats, g1, be1);

    // ---- layer 2
    hipMemsetAsync(agg, 0, featB, stream);
    scatter_add_kernel<<<scatterBlocks, 256, 0, stream>>>(hA, srcp, dstp, agg);
    gemm_fused_kernel<<<gemmBlocks, 256, 0, stream>>>(hA, agg, wr2, wl2, b2, hB);
    hipMemsetAsync(stats, 0, 1024, stream);
    col_stats_kernel<<<512, 128, 0, stream>>>(hB, stats);
    bn_act_kernel<true><<<bnBlocks, 256, 0, stream>>>(hB, stats, g2, be2);

    // ---- layer 3
    hipMemsetAsync(agg, 0, featB, stream);
    scatter_add_kernel<<<scatterBlocks, 256, 0, stream>>>(hB, srcp, dstp, agg);
    gemm_fused_kernel<<<gemmBlocks, 256, 0, stream>>>(hB, agg, wr3, wl3, b3, hA);
    hipMemsetAsync(stats, 0, 1024, stream);
    col_stats_kernel<<<512, 128, 0, stream>>>(hA, stats);
    bn_act_kernel<false><<<bnBlocks, 256, 0, stream>>>(hA, stats, g3, be3);

    // ---- pool + classify
    hipMemsetAsync(pooled, 0, (size_t)NG * DH * sizeof(float) + NG * sizeof(int), stream);
    pool_kernel<<<poolBlocks, 256, 0, stream>>>(hA, batch, pooled, counts);
    classify_kernel<<<NG, 64, 0, stream>>>(pooled, counts, wcls, bcls, out);
}

// Round 2
// 727.101 us; speedup vs baseline: 6.1636x; 6.1636x over previous
//
#include <hip/hip_runtime.h>

// GNN: 3x (GraphConv -> BatchNorm -> ReLU) -> global_mean_pool -> Linear
// All fp32. Integer inputs arrive as int32.
//
// Strategy: build CSR (edges bucketed by dst) ONCE per call, then per layer do
// an atomic-free gather-side aggregation. Pool uses sorted `batch` via
// segmented reduction (no atomics on floats anywhere).

constexpr int   NN   = 50000;
constexpr int   NE   = 800000;
constexpr int   DH   = 128;
constexpr int   NC   = 10;
constexpr int   NG   = 1024;
constexpr float EPSV = 1e-5f;

// ------------------------------------------------------------- CSR build ---
__global__ __launch_bounds__(256) void hist_kernel(
    const int* __restrict__ dst, int* __restrict__ deg)
{
    int e = blockIdx.x * 256 + threadIdx.x;
    if (e < NE) atomicAdd(&deg[dst[e]], 1);
}

__global__ __launch_bounds__(1024) void scan_kernel(
    const int* __restrict__ deg, int* __restrict__ offsets,
    int* __restrict__ cursor)
{
    __shared__ int part[1024];
    const int CH = (NN + 1023) / 1024;   // 49
    int t = threadIdx.x;
    int beg = t * CH;
    int lim = min(beg + CH, NN);
    int s = 0;
    for (int i = beg; i < lim; ++i) s += deg[i];
    part[t] = s;
    __syncthreads();
    for (int off = 1; off < 1024; off <<= 1) {
        int v = (t >= off) ? part[t - off] : 0;
        __syncthreads();
        part[t] += v;
        __syncthreads();
    }
    int base = (t == 0) ? 0 : part[t - 1];
    for (int i = beg; i < lim; ++i) {
        offsets[i] = base;
        cursor[i]  = base;
        base += deg[i];
    }
    if (t == 1023) offsets[NN] = base;
}

__global__ __launch_bounds__(256) void reorder_kernel(
    const int* __restrict__ src, const int* __restrict__ dst,
    int* __restrict__ cursor, int* __restrict__ csr_src)
{
    int e = blockIdx.x * 256 + threadIdx.x;
    if (e < NE) {
        int pos = atomicAdd(&cursor[dst[e]], 1);
        csr_src[pos] = src[e];
    }
}

// -------------------------------------------------------------- aggregate ---
// 32 lanes per node, float4 per lane; register accumulation, no atomics.
__global__ __launch_bounds__(256) void aggregate_kernel(
    const float* __restrict__ x, const int* __restrict__ offsets,
    const int* __restrict__ csr_src, float* __restrict__ agg)
{
    int tid = blockIdx.x * 256 + threadIdx.x;
    int node = tid >> 5;
    if (node >= NN) return;
    int c4 = (tid & 31) << 2;
    int beg = offsets[node], end = offsets[node + 1];
    float4 acc = make_float4(0.f, 0.f, 0.f, 0.f);
    int e = beg;
    for (; e + 1 < end; e += 2) {   // 2-way ILP on the gathers
        int s0 = csr_src[e], s1 = csr_src[e + 1];
        float4 v0 = *reinterpret_cast<const float4*>(x + (size_t)s0 * DH + c4);
        float4 v1 = *reinterpret_cast<const float4*>(x + (size_t)s1 * DH + c4);
        acc.x += v0.x + v1.x; acc.y += v0.y + v1.y;
        acc.z += v0.z + v1.z; acc.w += v0.w + v1.w;
    }
    if (e < end) {
        int s0 = csr_src[e];
        float4 v0 = *reinterpret_cast<const float4*>(x + (size_t)s0 * DH + c4);
        acc.x += v0.x; acc.y += v0.y; acc.z += v0.z; acc.w += v0.w;
    }
    *reinterpret_cast<float4*>(agg + (size_t)node * DH + c4) = acc;
}

// ------------------------------------------------------------------- gemm ---
// OUT(N x 128) = X @ Wr + A @ Wl + bias   (concat K = 256)
__global__ __launch_bounds__(256) void gemm_fused_kernel(
    const float* __restrict__ X, const float* __restrict__ A,
    const float* __restrict__ Wr, const float* __restrict__ Wl,
    const float* __restrict__ bias, float* __restrict__ OUT)
{
    __shared__ float sA[64][33];
    __shared__ float sW[32][128];

    const int tid = threadIdx.x;
    const int tx8 = (tid & 15) * 8;
    const int ty4 = (tid >> 4) * 4;
    const int row0 = blockIdx.x * 64;

    float acc[4][8];
#pragma unroll
    for (int r = 0; r < 4; ++r)
#pragma unroll
        for (int j = 0; j < 8; ++j) acc[r][j] = 0.f;

    const int rA = tid >> 2;
    const int cA = (tid & 3) * 4;

    for (int k0 = 0; k0 < 256; k0 += 32) {
        const float* inp = (k0 < 128) ? X : A;
        const float* W   = (k0 < 128) ? Wr : Wl;
        const int kb = k0 & 127;

        {
            int grow = row0 + rA;
            float4 v0 = make_float4(0.f, 0.f, 0.f, 0.f), v1 = v0;
            if (grow < NN) {
                const float* p = inp + (size_t)grow * DH + kb + cA;
                v0 = *reinterpret_cast<const float4*>(p);
                v1 = *reinterpret_cast<const float4*>(p + 16);
            }
            sA[rA][cA + 0]  = v0.x; sA[rA][cA + 1]  = v0.y;
            sA[rA][cA + 2]  = v0.z; sA[rA][cA + 3]  = v0.w;
            sA[rA][cA + 16] = v1.x; sA[rA][cA + 17] = v1.y;
            sA[rA][cA + 18] = v1.z; sA[rA][cA + 19] = v1.w;
        }
#pragma unroll
        for (int i = 0; i < 4; ++i) {
            int idx = tid + i * 256;
            int kk = idx >> 5;
            int cc = (idx & 31) * 4;
            *reinterpret_cast<float4*>(&sW[kk][cc]) =
                *reinterpret_cast<const float4*>(W + (size_t)(kb + kk) * DH + cc);
        }
        __syncthreads();

#pragma unroll 8
        for (int kk = 0; kk < 32; ++kk) {
            float a0 = sA[ty4 + 0][kk];
            float a1 = sA[ty4 + 1][kk];
            float a2 = sA[ty4 + 2][kk];
            float a3 = sA[ty4 + 3][kk];
            float4 w0 = *reinterpret_cast<const float4*>(&sW[kk][tx8]);
            float4 w1 = *reinterpret_cast<const float4*>(&sW[kk][tx8 + 4]);
            float wv[8] = {w0.x, w0.y, w0.z, w0.w, w1.x, w1.y, w1.z, w1.w};
#pragma unroll
            for (int j = 0; j < 8; ++j) {
                acc[0][j] = fmaf(a0, wv[j], acc[0][j]);
                acc[1][j] = fmaf(a1, wv[j], acc[1][j]);
                acc[2][j] = fmaf(a2, wv[j], acc[2][j]);
                acc[3][j] = fmaf(a3, wv[j], acc[3][j]);
            }
        }
        __syncthreads();
    }

    float bv[8];
#pragma unroll
    for (int j = 0; j < 8; ++j) bv[j] = bias[tx8 + j];

#pragma unroll
    for (int r = 0; r < 4; ++r) {
        int grow = row0 + ty4 + r;
        if (grow < NN) {
            float4 o0, o1;
            o0.x = acc[r][0] + bv[0]; o0.y = acc[r][1] + bv[1];
            o0.z = acc[r][2] + bv[2]; o0.w = acc[r][3] + bv[3];
            o1.x = acc[r][4] + bv[4]; o1.y = acc[r][5] + bv[5];
            o1.z = acc[r][6] + bv[6]; o1.w = acc[r][7] + bv[7];
            float* op = OUT + (size_t)grow * DH + tx8;
            *reinterpret_cast<float4*>(op)     = o0;
            *reinterpret_cast<float4*>(op + 4) = o1;
        }
    }
}

// ------------------------------------------------------------------ stats ---
__global__ __launch_bounds__(128) void col_stats_kernel(
    const float* __restrict__ H, float* __restrict__ stats)
{
    int col = threadIdx.x;
    float s = 0.f, ss = 0.f;
    for (int r = blockIdx.x; r < NN; r += gridDim.x) {
        float v = H[(size_t)r * DH + col];
        s += v;
        ss += v * v;
    }
    atomicAdd(&stats[col], s);
    atomicAdd(&stats[DH + col], ss);
}

template <bool RELU>
__global__ __launch_bounds__(256) void bn_act_kernel(
    float* __restrict__ Hio, const float* __restrict__ stats,
    const float* __restrict__ gamma, const float* __restrict__ beta)
{
    __shared__ float sscale[DH], sshift[DH];
    if (threadIdx.x < DH) {
        int j = threadIdx.x;
        float mean = stats[j] * (1.f / NN);
        float var  = stats[DH + j] * (1.f / NN) - mean * mean;
        float sc = rsqrtf(var + EPSV) * gamma[j];
        sscale[j] = sc;
        sshift[j] = beta[j] - mean * sc;
    }
    __syncthreads();

    const int total4 = NN * (DH / 4);
    for (int i = blockIdx.x * 256 + threadIdx.x; i < total4; i += gridDim.x * 256) {
        float4 v = reinterpret_cast<float4*>(Hio)[i];
        int j0 = (i & 31) * 4;
        v.x = v.x * sscale[j0 + 0] + sshift[j0 + 0];
        v.y = v.y * sscale[j0 + 1] + sshift[j0 + 1];
        v.z = v.z * sscale[j0 + 2] + sshift[j0 + 2];
        v.w = v.w * sscale[j0 + 3] + sshift[j0 + 3];
        if (RELU) {
            v.x = fmaxf(v.x, 0.f); v.y = fmaxf(v.y, 0.f);
            v.z = fmaxf(v.z, 0.f); v.w = fmaxf(v.w, 0.f);
        }
        reinterpret_cast<float4*>(Hio)[i] = v;
    }
}

// ------------------------------------------------------------------- pool ---
__global__ __launch_bounds__(256) void ghist_kernel(
    const int* __restrict__ batch, int* __restrict__ gdeg)
{
    int n = blockIdx.x * 256 + threadIdx.x;
    if (n < NN) atomicAdd(&gdeg[batch[n]], 1);
}

__global__ __launch_bounds__(1024) void gscan_kernel(
    const int* __restrict__ gdeg, int* __restrict__ goff)
{
    __shared__ int part[1024];
    int t = threadIdx.x;
    part[t] = gdeg[t];
    __syncthreads();
    for (int off = 1; off < 1024; off <<= 1) {
        int v = (t >= off) ? part[t - off] : 0;
        __syncthreads();
        part[t] += v;
        __syncthreads();
    }
    goff[t + 1] = part[t];
    if (t == 0) goff[0] = 0;
}

// batch is sorted: nodes of graph g are rows [goff[g], goff[g+1])
__global__ __launch_bounds__(128) void pool_seg_kernel(
    const float* __restrict__ H, const int* __restrict__ goff,
    float* __restrict__ pooled)
{
    int g = blockIdx.x;
    int j = threadIdx.x;
    int beg = goff[g], end = goff[g + 1];
    float s = 0.f;
    for (int n = beg; n < end; ++n) s += H[(size_t)n * DH + j];
    float cnt = (float)(end - beg);
    pooled[(size_t)g * DH + j] = s / fmaxf(cnt, 1.f);
}

__global__ __launch_bounds__(64) void classify_kernel(
    const float* __restrict__ pooled, const float* __restrict__ wcls,
    const float* __restrict__ bcls, float* __restrict__ out)
{
    int g = blockIdx.x;
    int lane = threadIdx.x;
    float p0 = pooled[(size_t)g * DH + lane];
    float p1 = pooled[(size_t)g * DH + 64 + lane];
#pragma unroll
    for (int c = 0; c < NC; ++c) {
        float v = p0 * wcls[lane * NC + c] + p1 * wcls[(64 + lane) * NC + c];
#pragma unroll
        for (int off = 32; off > 0; off >>= 1) v += __shfl_down(v, off, 64);
        if (lane == 0) out[(size_t)g * NC + c] = v + bcls[c];
    }
}

// ----------------------------------------------------------------- launch ---
extern "C" void kernel_launch(void* const* d_in, const int* in_sizes, int n_in,
                              void* d_out, int out_size, void* d_ws, size_t ws_size,
                              hipStream_t stream)
{
    const float* x    = (const float*)d_in[0];
    const int*   ei   = (const int*)d_in[1];
    const int*   batch= (const int*)d_in[2];
    const float* wr1  = (const float*)d_in[3];
    const float* wl1  = (const float*)d_in[4];
    const float* b1   = (const float*)d_in[5];
    const float* wr2  = (const float*)d_in[6];
    const float* wl2  = (const float*)d_in[7];
    const float* b2   = (const float*)d_in[8];
    const float* wr3  = (const float*)d_in[9];
    const float* wl3  = (const float*)d_in[10];
    const float* b3   = (const float*)d_in[11];
    const float* g1   = (const float*)d_in[12];
    const float* be1  = (const float*)d_in[13];
    const float* g2   = (const float*)d_in[14];
    const float* be2  = (const float*)d_in[15];
    const float* g3   = (const float*)d_in[16];
    const float* be3  = (const float*)d_in[17];
    const float* wcls = (const float*)d_in[18];
    const float* bcls = (const float*)d_in[19];
    float* out = (float*)d_out;

    const int* srcp = ei;
    const int* dstp = ei + NE;

    char* ws = (char*)d_ws;
    const size_t featB = (size_t)NN * DH * sizeof(float);   // 25,600,000 B
    size_t off = 0;
    auto alloc = [&](size_t bytes) {
        void* p = ws + off;
        off += (bytes + 255) & ~(size_t)255;
        return p;
    };
    float* agg     = (float*)alloc(featB);
    float* hA      = (float*)alloc(featB);
    float* hB      = (float*)alloc(featB);
    float* stats   = (float*)alloc(1024);
    float* pooled  = (float*)alloc((size_t)NG * DH * sizeof(float));
    int*   deg     = (int*)alloc(NN * sizeof(int));
    int*   offsets = (int*)alloc((NN + 1) * sizeof(int));
    int*   cursor  = (int*)alloc(NN * sizeof(int));
    int*   csr_src = (int*)alloc(NE * sizeof(int));
    int*   gdeg    = (int*)alloc(NG * sizeof(int));
    int*   goff    = (int*)alloc((NG + 1) * sizeof(int));

    const int edgeBlocks = (NE + 255) / 256;     // 3125
    const int nodeBlocks = (NN + 255) / 256;     // 196
    const int aggBlocks  = (NN * 32 + 255) / 256;
    const int gemmBlocks = (NN + 63) / 64;
    const int bnBlocks   = 2048;

    // ---- CSR build (once; reused by all 3 layers)
    hipMemsetAsync(deg, 0, NN * sizeof(int), stream);
    hist_kernel<<<edgeBlocks, 256, 0, stream>>>(dstp, deg);
    scan_kernel<<<1, 1024, 0, stream>>>(deg, offsets, cursor);
    reorder_kernel<<<edgeBlocks, 256, 0, stream>>>(srcp, dstp, cursor, csr_src);

    // ---- graph ranges for pooling (batch is sorted)
    hipMemsetAsync(gdeg, 0, NG * sizeof(int), stream);
    ghist_kernel<<<nodeBlocks, 256, 0, stream>>>(batch, gdeg);
    gscan_kernel<<<1, 1024, 0, stream>>>(gdeg, goff);

    // ---- layer 1
    aggregate_kernel<<<aggBlocks, 256, 0, stream>>>(x, offsets, csr_src, agg);
    gemm_fused_kernel<<<gemmBlocks, 256, 0, stream>>>(x, agg, wr1, wl1, b1, hA);
    hipMemsetAsync(stats, 0, 1024, stream);
    col_stats_kernel<<<512, 128, 0, stream>>>(hA, stats);
    bn_act_kernel<true><<<bnBlocks, 256, 0, stream>>>(hA, stats, g1, be1);

    // ---- layer 2
    aggregate_kernel<<<aggBlocks, 256, 0, stream>>>(hA, offsets, csr_src, agg);
    gemm_fused_kernel<<<gemmBlocks, 256, 0, stream>>>(hA, agg, wr2, wl2, b2, hB);
    hipMemsetAsync(stats, 0, 1024, stream);
    col_stats_kernel<<<512, 128, 0, stream>>>(hB, stats);
    bn_act_kernel<true><<<bnBlocks, 256, 0, stream>>>(hB, stats, g2, be2);

    // ---- layer 3
    aggregate_kernel<<<aggBlocks, 256, 0, stream>>>(hB, offsets, csr_src, agg);
    gemm_fused_kernel<<<gemmBlocks, 256, 0, stream>>>(hB, agg, wr3, wl3, b3, hA);
    hipMemsetAsync(stats, 0, 1024, stream);
    col_stats_kernel<<<512, 128, 0, stream>>>(hA, stats);
    bn_act_kernel<false><<<bnBlocks, 256, 0, stream>>>(hA, stats, g3, be3);

    // ---- pool + classify
    pool_seg_kernel<<<NG, 128, 0, stream>>>(hA, goff, pooled);
    classify_kernel<<<NG, 64, 0, stream>>>(pooled, wcls, bcls, out);
}

// Round 3
// 510.501 us; speedup vs baseline: 8.7788x; 1.4243x over previous
//
#include <hip/hip_runtime.h>

// GNN: 3x (GraphConv -> BatchNorm -> ReLU) -> global_mean_pool -> Linear, fp32.
//
// Structure:
//  - CSR build once (hist -> parallel 3-stage scan -> reorder), reused 3x.
//  - Per layer: aggregate (gather-side, atomic-free, lazy BN+ReLU of previous
//    layer applied per gathered element) -> fused GEMM (concat-K 256, lazy BN
//    on X path, col-stats accumulated in epilogue) -> tiny finalize kernel
//    computing (scale, shift) for the *next* consumer.
//  - Pool applies layer-3 (scale, shift) (no ReLU), segmented over sorted batch.

constexpr int   NN   = 50000;
constexpr int   NE   = 800000;
constexpr int   DH   = 128;
constexpr int   NC   = 10;
constexpr int   NG   = 1024;
constexpr float EPSV = 1e-5f;
constexpr int   NB   = (NN + 255) / 256;   // 196 scan blocks

// ------------------------------------------------------------- CSR build ---
__global__ __launch_bounds__(256) void hist_kernel(
    const int* __restrict__ dst, int* __restrict__ deg)
{
    int e = blockIdx.x * 256 + threadIdx.x;
    if (e < NE) atomicAdd(&deg[dst[e]], 1);
}

__global__ __launch_bounds__(256) void psum_kernel(
    const int* __restrict__ deg, int* __restrict__ bsum)
{
    int t = threadIdx.x;
    int i = blockIdx.x * 256 + t;
    int d = (i < NN) ? deg[i] : 0;
#pragma unroll
    for (int off = 32; off > 0; off >>= 1) d += __shfl_down(d, off, 64);
    __shared__ int w4[4];
    if ((t & 63) == 0) w4[t >> 6] = d;
    __syncthreads();
    if (t == 0) bsum[blockIdx.x] = w4[0] + w4[1] + w4[2] + w4[3];
}

__global__ __launch_bounds__(256) void scan_bsums_kernel(
    const int* __restrict__ bsum, int* __restrict__ bbase)
{
    __shared__ int tmp[256];
    int t = threadIdx.x;
    int v = (t < NB) ? bsum[t] : 0;
    tmp[t] = v;
    __syncthreads();
    for (int off = 1; off < 256; off <<= 1) {
        int u = (t >= off) ? tmp[t - off] : 0;
        __syncthreads();
        tmp[t] += u;
        __syncthreads();
    }
    if (t < NB) bbase[t] = tmp[t] - v;   // exclusive
}

__global__ __launch_bounds__(256) void offsets_kernel(
    const int* __restrict__ deg, const int* __restrict__ bbase,
    int* __restrict__ offsets, int* __restrict__ cursor)
{
    __shared__ int tmp[256];
    int t = threadIdx.x;
    int i = blockIdx.x * 256 + t;
    int d = (i < NN) ? deg[i] : 0;
    tmp[t] = d;
    __syncthreads();
    for (int off = 1; off < 256; off <<= 1) {
        int u = (t >= off) ? tmp[t - off] : 0;
        __syncthreads();
        tmp[t] += u;
        __syncthreads();
    }
    int incl = tmp[t];
    int base = bbase[blockIdx.x];
    if (i < NN) {
        int o = base + incl - d;
        offsets[i] = o;
        cursor[i]  = o;
        if (i == NN - 1) offsets[NN] = base + incl;
    }
}

__global__ __launch_bounds__(256) void reorder_kernel(
    const int* __restrict__ src, const int* __restrict__ dst,
    int* __restrict__ cursor, int* __restrict__ csr_src)
{
    int e = blockIdx.x * 256 + threadIdx.x;
    if (e < NE) {
        int pos = atomicAdd(&cursor[dst[e]], 1);
        csr_src[pos] = src[e];
    }
}

// -------------------------------------------------------------- aggregate ---
// 32 lanes per node, float4 per lane; 4-edge unroll. TRANSFORM applies the
// previous layer's lazy BN+ReLU per gathered element.
template <bool TRANSFORM>
__global__ __launch_bounds__(256) void aggregate_kernel(
    const float* __restrict__ x, const int* __restrict__ offsets,
    const int* __restrict__ csr_src, const float* __restrict__ sc,
    const float* __restrict__ sh, float* __restrict__ agg)
{
    int tid = blockIdx.x * 256 + threadIdx.x;
    int node = tid >> 5;
    if (node >= NN) return;
    int c4 = (tid & 31) << 2;

    float4 sc4, sh4;
    if (TRANSFORM) {
        sc4 = *reinterpret_cast<const float4*>(sc + c4);
        sh4 = *reinterpret_cast<const float4*>(sh + c4);
    }
    auto xf = [&](float4 v) -> float4 {
        if (TRANSFORM) {
            v.x = fmaxf(fmaf(v.x, sc4.x, sh4.x), 0.f);
            v.y = fmaxf(fmaf(v.y, sc4.y, sh4.y), 0.f);
            v.z = fmaxf(fmaf(v.z, sc4.z, sh4.z), 0.f);
            v.w = fmaxf(fmaf(v.w, sc4.w, sh4.w), 0.f);
        }
        return v;
    };

    int beg = offsets[node], end = offsets[node + 1];
    float4 acc = make_float4(0.f, 0.f, 0.f, 0.f);
    int e = beg;
    for (; e + 3 < end; e += 4) {
        int s0 = csr_src[e], s1 = csr_src[e + 1];
        int s2 = csr_src[e + 2], s3 = csr_src[e + 3];
        float4 v0 = xf(*reinterpret_cast<const float4*>(x + (size_t)s0 * DH + c4));
        float4 v1 = xf(*reinterpret_cast<const float4*>(x + (size_t)s1 * DH + c4));
        float4 v2 = xf(*reinterpret_cast<const float4*>(x + (size_t)s2 * DH + c4));
        float4 v3 = xf(*reinterpret_cast<const float4*>(x + (size_t)s3 * DH + c4));
        acc.x += (v0.x + v1.x) + (v2.x + v3.x);
        acc.y += (v0.y + v1.y) + (v2.y + v3.y);
        acc.z += (v0.z + v1.z) + (v2.z + v3.z);
        acc.w += (v0.w + v1.w) + (v2.w + v3.w);
    }
    for (; e < end; ++e) {
        int s0 = csr_src[e];
        float4 v0 = xf(*reinterpret_cast<const float4*>(x + (size_t)s0 * DH + c4));
        acc.x += v0.x; acc.y += v0.y; acc.z += v0.z; acc.w += v0.w;
    }
    *reinterpret_cast<float4*>(agg + (size_t)node * DH + c4) = acc;
}

// ------------------------------------------------------------------- gemm ---
// OUT = t(X) @ Wr + A @ Wl + bias, t = lazy BN+ReLU (TRANSFORM) or identity.
// Epilogue accumulates column sum/sumsq of OUT into stats[256] via atomics.
template <bool TRANSFORM>
__global__ __launch_bounds__(256) void gemm_fused_kernel(
    const float* __restrict__ X, const float* __restrict__ A,
    const float* __restrict__ Wr, const float* __restrict__ Wl,
    const float* __restrict__ bias, const float* __restrict__ scIn,
    const float* __restrict__ shIn, float* __restrict__ OUT,
    float* __restrict__ stats)
{
    __shared__ float sA[64][33];
    __shared__ float sW[32][128];
    __shared__ float sScale[DH], sShift[DH];
    __shared__ float ldsS[4][DH], ldsQ[4][DH];

    const int tid = threadIdx.x;
    const int tx8 = (tid & 15) * 8;
    const int ty4 = (tid >> 4) * 4;
    const int row0 = blockIdx.x * 64;

    if (TRANSFORM && tid < DH) {
        sScale[tid] = scIn[tid];
        sShift[tid] = shIn[tid];
    }
    __syncthreads();

    float acc[4][8];
#pragma unroll
    for (int r = 0; r < 4; ++r)
#pragma unroll
        for (int j = 0; j < 8; ++j) acc[r][j] = 0.f;

    const int rA = tid >> 2;
    const int cA = (tid & 3) * 4;

    for (int k0 = 0; k0 < 256; k0 += 32) {
        const float* inp = (k0 < 128) ? X : A;
        const float* W   = (k0 < 128) ? Wr : Wl;
        const int kb = k0 & 127;

        {
            int grow = row0 + rA;
            float4 v0 = make_float4(0.f, 0.f, 0.f, 0.f), v1 = v0;
            if (grow < NN) {
                const float* p = inp + (size_t)grow * DH + kb + cA;
                v0 = *reinterpret_cast<const float4*>(p);
                v1 = *reinterpret_cast<const float4*>(p + 16);
                if (TRANSFORM && k0 < 128) {
                    int cb = kb + cA;
                    v0.x = fmaxf(fmaf(v0.x, sScale[cb + 0],  sShift[cb + 0]),  0.f);
                    v0.y = fmaxf(fmaf(v0.y, sScale[cb + 1],  sShift[cb + 1]),  0.f);
                    v0.z = fmaxf(fmaf(v0.z, sScale[cb + 2],  sShift[cb + 2]),  0.f);
                    v0.w = fmaxf(fmaf(v0.w, sScale[cb + 3],  sShift[cb + 3]),  0.f);
                    v1.x = fmaxf(fmaf(v1.x, sScale[cb + 16], sShift[cb + 16]), 0.f);
                    v1.y = fmaxf(fmaf(v1.y, sScale[cb + 17], sShift[cb + 17]), 0.f);
                    v1.z = fmaxf(fmaf(v1.z, sScale[cb + 18], sShift[cb + 18]), 0.f);
                    v1.w = fmaxf(fmaf(v1.w, sScale[cb + 19], sShift[cb + 19]), 0.f);
                }
            }
            sA[rA][cA + 0]  = v0.x; sA[rA][cA + 1]  = v0.y;
            sA[rA][cA + 2]  = v0.z; sA[rA][cA + 3]  = v0.w;
            sA[rA][cA + 16] = v1.x; sA[rA][cA + 17] = v1.y;
            sA[rA][cA + 18] = v1.z; sA[rA][cA + 19] = v1.w;
        }
#pragma unroll
        for (int i = 0; i < 4; ++i) {
            int idx = tid + i * 256;
            int kk = idx >> 5;
            int cc = (idx & 31) * 4;
            *reinterpret_cast<float4*>(&sW[kk][cc]) =
                *reinterpret_cast<const float4*>(W + (size_t)(kb + kk) * DH + cc);
        }
        __syncthreads();

#pragma unroll 8
        for (int kk = 0; kk < 32; ++kk) {
            float a0 = sA[ty4 + 0][kk];
            float a1 = sA[ty4 + 1][kk];
            float a2 = sA[ty4 + 2][kk];
            float a3 = sA[ty4 + 3][kk];
            float4 w0 = *reinterpret_cast<const float4*>(&sW[kk][tx8]);
            float4 w1 = *reinterpret_cast<const float4*>(&sW[kk][tx8 + 4]);
            float wv[8] = {w0.x, w0.y, w0.z, w0.w, w1.x, w1.y, w1.z, w1.w};
#pragma unroll
            for (int j = 0; j < 8; ++j) {
                acc[0][j] = fmaf(a0, wv[j], acc[0][j]);
                acc[1][j] = fmaf(a1, wv[j], acc[1][j]);
                acc[2][j] = fmaf(a2, wv[j], acc[2][j]);
                acc[3][j] = fmaf(a3, wv[j], acc[3][j]);
            }
        }
        __syncthreads();
    }

    float bv[8];
#pragma unroll
    for (int j = 0; j < 8; ++j) bv[j] = bias[tx8 + j];

    float s_[8], q_[8];
#pragma unroll
    for (int j = 0; j < 8; ++j) { s_[j] = 0.f; q_[j] = 0.f; }

#pragma unroll
    for (int r = 0; r < 4; ++r) {
        int grow = row0 + ty4 + r;
        if (grow < NN) {
            float o[8];
#pragma unroll
            for (int j = 0; j < 8; ++j) {
                o[j] = acc[r][j] + bv[j];
                s_[j] += o[j];
                q_[j] += o[j] * o[j];
            }
            float* op = OUT + (size_t)grow * DH + tx8;
            float4 o0 = make_float4(o[0], o[1], o[2], o[3]);
            float4 o1 = make_float4(o[4], o[5], o[6], o[7]);
            *reinterpret_cast<float4*>(op)     = o0;
            *reinterpret_cast<float4*>(op + 4) = o1;
        }
    }

    // stats reduction: lanes {l, l+16, l+32, l+48} share columns
#pragma unroll
    for (int j = 0; j < 8; ++j) {
        s_[j] += __shfl_xor(s_[j], 16, 64);
        s_[j] += __shfl_xor(s_[j], 32, 64);
        q_[j] += __shfl_xor(q_[j], 16, 64);
        q_[j] += __shfl_xor(q_[j], 32, 64);
    }
    int lane = tid & 63, wave = tid >> 6;
    if (lane < 16) {
#pragma unroll
        for (int j = 0; j < 8; ++j) {
            ldsS[wave][lane * 8 + j] = s_[j];
            ldsQ[wave][lane * 8 + j] = q_[j];
        }
    }
    __syncthreads();
    if (tid < DH) {
        float s = ldsS[0][tid] + ldsS[1][tid] + ldsS[2][tid] + ldsS[3][tid];
        float q = ldsQ[0][tid] + ldsQ[1][tid] + ldsQ[2][tid] + ldsQ[3][tid];
        atomicAdd(&stats[tid], s);
        atomicAdd(&stats[DH + tid], q);
    }
}

// --------------------------------------------------------------- finalize ---
__global__ __launch_bounds__(128) void finalize_kernel(
    const float* __restrict__ stats, const float* __restrict__ gamma,
    const float* __restrict__ beta, float* __restrict__ sc,
    float* __restrict__ sh)
{
    int j = threadIdx.x;
    float mean = stats[j] * (1.f / NN);
    float var  = stats[DH + j] * (1.f / NN) - mean * mean;
    float s = rsqrtf(var + EPSV) * gamma[j];
    sc[j] = s;
    sh[j] = beta[j] - mean * s;
}

// ------------------------------------------------------------------- pool ---
__global__ __launch_bounds__(256) void ghist_kernel(
    const int* __restrict__ batch, int* __restrict__ gdeg)
{
    int n = blockIdx.x * 256 + threadIdx.x;
    if (n < NN) atomicAdd(&gdeg[batch[n]], 1);
}

__global__ __launch_bounds__(1024) void gscan_kernel(
    const int* __restrict__ gdeg, int* __restrict__ goff)
{
    __shared__ int part[1024];
    int t = threadIdx.x;
    part[t] = gdeg[t];
    __syncthreads();
    for (int off = 1; off < 1024; off <<= 1) {
        int v = (t >= off) ? part[t - off] : 0;
        __syncthreads();
        part[t] += v;
        __syncthreads();
    }
    goff[t + 1] = part[t];
    if (t == 0) goff[0] = 0;
}

// batch sorted: graph g owns rows [goff[g], goff[g+1]). Applies layer-3 BN
// (no ReLU) lazily, then mean.
__global__ __launch_bounds__(128) void pool_seg_kernel(
    const float* __restrict__ H, const int* __restrict__ goff,
    const float* __restrict__ sc, const float* __restrict__ sh,
    float* __restrict__ pooled)
{
    int g = blockIdx.x;
    int j = threadIdx.x;
    int beg = goff[g], end = goff[g + 1];
    float s = 0.f;
    for (int n = beg; n < end; ++n) s += H[(size_t)n * DH + j];
    float cnt = (float)(end - beg);
    float v = s * sc[j] + cnt * sh[j];
    pooled[(size_t)g * DH + j] = v / fmaxf(cnt, 1.f);
}

__global__ __launch_bounds__(64) void classify_kernel(
    const float* __restrict__ pooled, const float* __restrict__ wcls,
    const float* __restrict__ bcls, float* __restrict__ out)
{
    int g = blockIdx.x;
    int lane = threadIdx.x;
    float p0 = pooled[(size_t)g * DH + lane];
    float p1 = pooled[(size_t)g * DH + 64 + lane];
#pragma unroll
    for (int c = 0; c < NC; ++c) {
        float v = p0 * wcls[lane * NC + c] + p1 * wcls[(64 + lane) * NC + c];
#pragma unroll
        for (int off = 32; off > 0; off >>= 1) v += __shfl_down(v, off, 64);
        if (lane == 0) out[(size_t)g * NC + c] = v + bcls[c];
    }
}

// ----------------------------------------------------------------- launch ---
extern "C" void kernel_launch(void* const* d_in, const int* in_sizes, int n_in,
                              void* d_out, int out_size, void* d_ws, size_t ws_size,
                              hipStream_t stream)
{
    const float* x    = (const float*)d_in[0];
    const int*   ei   = (const int*)d_in[1];
    const int*   batch= (const int*)d_in[2];
    const float* wr1  = (const float*)d_in[3];
    const float* wl1  = (const float*)d_in[4];
    const float* b1   = (const float*)d_in[5];
    const float* wr2  = (const float*)d_in[6];
    const float* wl2  = (const float*)d_in[7];
    const float* b2   = (const float*)d_in[8];
    const float* wr3  = (const float*)d_in[9];
    const float* wl3  = (const float*)d_in[10];
    const float* b3   = (const float*)d_in[11];
    const float* g1   = (const float*)d_in[12];
    const float* be1  = (const float*)d_in[13];
    const float* g2   = (const float*)d_in[14];
    const float* be2  = (const float*)d_in[15];
    const float* g3   = (const float*)d_in[16];
    const float* be3  = (const float*)d_in[17];
    const float* wcls = (const float*)d_in[18];
    const float* bcls = (const float*)d_in[19];
    float* out = (float*)d_out;

    const int* srcp = ei;
    const int* dstp = ei + NE;

    char* ws = (char*)d_ws;
    const size_t featB = (size_t)NN * DH * sizeof(float);
    size_t off = 0;
    auto alloc = [&](size_t bytes) {
        void* p = ws + off;
        off += (bytes + 255) & ~(size_t)255;
        return p;
    };
    float* agg     = (float*)alloc(featB);
    float* hA      = (float*)alloc(featB);
    float* hB      = (float*)alloc(featB);
    float* stats   = (float*)alloc(1024);
    float* pooled  = (float*)alloc((size_t)NG * DH * sizeof(float));
    int*   deg     = (int*)alloc(NN * sizeof(int));
    int*   offsets = (int*)alloc((NN + 1) * sizeof(int));
    int*   cursor  = (int*)alloc(NN * sizeof(int));
    int*   csr_src = (int*)alloc(NE * sizeof(int));
    int*   gdeg    = (int*)alloc(NG * sizeof(int));
    int*   goff    = (int*)alloc((NG + 1) * sizeof(int));
    int*   bsum    = (int*)alloc(NB * sizeof(int));
    int*   bbase   = (int*)alloc(NB * sizeof(int));
    float* sc1 = (float*)alloc(DH * 4); float* sh1 = (float*)alloc(DH * 4);
    float* sc2 = (float*)alloc(DH * 4); float* sh2 = (float*)alloc(DH * 4);
    float* sc3 = (float*)alloc(DH * 4); float* sh3 = (float*)alloc(DH * 4);

    const int edgeBlocks = (NE + 255) / 256;
    const int nodeBlocks = (NN + 255) / 256;     // == NB
    const int aggBlocks  = (NN * 32 + 255) / 256;
    const int gemmBlocks = (NN + 63) / 64;

    // ---- CSR build (once)
    hipMemsetAsync(deg, 0, NN * sizeof(int), stream);
    hist_kernel<<<edgeBlocks, 256, 0, stream>>>(dstp, deg);
    psum_kernel<<<NB, 256, 0, stream>>>(deg, bsum);
    scan_bsums_kernel<<<1, 256, 0, stream>>>(bsum, bbase);
    offsets_kernel<<<NB, 256, 0, stream>>>(deg, bbase, offsets, cursor);
    reorder_kernel<<<edgeBlocks, 256, 0, stream>>>(srcp, dstp, cursor, csr_src);

    // ---- graph ranges for pooling
    hipMemsetAsync(gdeg, 0, NG * sizeof(int), stream);
    ghist_kernel<<<nodeBlocks, 256, 0, stream>>>(batch, gdeg);
    gscan_kernel<<<1, 1024, 0, stream>>>(gdeg, goff);

    // ---- layer 1 (input x is untransformed)
    aggregate_kernel<false><<<aggBlocks, 256, 0, stream>>>(x, offsets, csr_src, nullptr, nullptr, agg);
    hipMemsetAsync(stats, 0, 1024, stream);
    gemm_fused_kernel<false><<<gemmBlocks, 256, 0, stream>>>(x, agg, wr1, wl1, b1, nullptr, nullptr, hA, stats);
    finalize_kernel<<<1, 128, 0, stream>>>(stats, g1, be1, sc1, sh1);

    // ---- layer 2 (consumes raw1=hA with t1 = BN1+ReLU)
    aggregate_kernel<true><<<aggBlocks, 256, 0, stream>>>(hA, offsets, csr_src, sc1, sh1, agg);
    hipMemsetAsync(stats, 0, 1024, stream);
    gemm_fused_kernel<true><<<gemmBlocks, 256, 0, stream>>>(hA, agg, wr2, wl2, b2, sc1, sh1, hB, stats);
    finalize_kernel<<<1, 128, 0, stream>>>(stats, g2, be2, sc2, sh2);

    // ---- layer 3 (consumes raw2=hB with t2 = BN2+ReLU)
    aggregate_kernel<true><<<aggBlocks, 256, 0, stream>>>(hB, offsets, csr_src, sc2, sh2, agg);
    hipMemsetAsync(stats, 0, 1024, stream);
    gemm_fused_kernel<true><<<gemmBlocks, 256, 0, stream>>>(hB, agg, wr3, wl3, b3, sc2, sh2, hA, stats);
    finalize_kernel<<<1, 128, 0, stream>>>(stats, g3, be3, sc3, sh3);

    // ---- pool (applies BN3, no ReLU) + classify
    pool_seg_kernel<<<NG, 128, 0, stream>>>(hA, goff, sc3, sh3, pooled);
    classify_kernel<<<NG, 64, 0, stream>>>(pooled, wcls, bcls, out);
}